// Round 4
// baseline (315.699 us; speedup 1.0000x reference)
//
#include <hip/hip_runtime.h>
#include <stdint.h>

// CrossAttentionHead: B=8, C=768, S=T=2304, D=512.
// transpose/cvt -> fused QKV GEMM (N=1536 concat) -> scores256 (256^2 tile,
// dbuf, T3-minimum issue-early schedule, exp epilogue + atomic row denom)
// -> PV GEMM (m97 128^2, 1/denom epilogue).
//
// Workspace (ushort elems):
//   Q[0,..) K[9437184,..) Vt[18874368,..)  (each 9,437,184)
//   P@28311552 (42,467,328 elems, 85MB); aliased inside P (dead before P):
//   xs@28311552, xts@42467328, wcat@56623104 (wq|wk|wv, 1536x768),
//   bcat(f32)@ushort 57802752; denom(f32,18432)@ushort 70778880.

typedef __bf16 bf16x8 __attribute__((ext_vector_type(8)));
typedef float f32x4 __attribute__((ext_vector_type(4)));

__device__ __forceinline__ unsigned short f2bf(float f) {
  union { float f; unsigned int u; } c; c.f = f;
  return (unsigned short)((c.u + 0x7fffu + ((c.u >> 16) & 1u)) >> 16); // RNE
}

// ---- weight fp32 -> bf16 ----
__global__ __launch_bounds__(256) void convw_kernel(const float* __restrict__ src,
                                                    unsigned short* __restrict__ dst, int n) {
  int i = (blockIdx.x * 256 + threadIdx.x) * 4;
  if (i + 3 < n) {
    const float4 v = *reinterpret_cast<const float4*>(src + i);
    dst[i + 0] = f2bf(v.x); dst[i + 1] = f2bf(v.y);
    dst[i + 2] = f2bf(v.z); dst[i + 3] = f2bf(v.w);
  }
}

// ---- zero denom + concat bias ----
__global__ __launch_bounds__(256) void init_kernel(const float* __restrict__ bq,
                                                   const float* __restrict__ bk,
                                                   const float* __restrict__ bv,
                                                   float* __restrict__ denom,
                                                   float* __restrict__ bcat) {
  int i = blockIdx.x * 256 + threadIdx.x;
  if (i < 18432) denom[i] = 0.0f;
  else if (i < 19968) {
    int k = i - 18432;
    bcat[k] = (k < 512) ? bq[k] : (k < 1024) ? bk[k - 512] : bv[k - 1024];
  }
}

// ---- x[b][c][s] fp32 -> xs[b][s][c] bf16 (64x64 LDS tiles) ----
__global__ __launch_bounds__(256) void transpose_bf16_kernel(
    const float* __restrict__ x, const float* __restrict__ xt,
    unsigned short* __restrict__ xs, unsigned short* __restrict__ xts) {
  const int S = 2304, C = 768;
  const int z = blockIdx.z;
  const float* src = (z < 8) ? x : xt;
  unsigned short* dst = (z < 8) ? xs : xts;
  const int b = z & 7;
  src += (size_t)b * C * S;
  dst += (size_t)b * S * C;
  __shared__ float tile[64][65];
  const int s0 = blockIdx.x * 64, c0 = blockIdx.y * 64;
  const int ls = threadIdx.x & 63, lr = threadIdx.x >> 6;
#pragma unroll
  for (int i = 0; i < 16; ++i) {
    const int c = lr + i * 4;
    tile[c][ls] = src[(size_t)(c0 + c) * S + s0 + ls];
  }
  __syncthreads();
#pragma unroll
  for (int i = 0; i < 16; ++i) {
    const int s = lr + i * 4;
    dst[(size_t)(s0 + s) * C + c0 + ls] = f2bf(tile[ls][s]);
  }
}

// ---- fused QKV projection: C[m][0..1536) = A @ wcat^T + bcat (m97 128^2) ----
// seg 0 -> Q[m][n], seg 1 -> K[m][n-512], seg 2 -> Vt[n-1024][m]
__global__ __launch_bounds__(256) void qkv_kernel(
    const unsigned short* __restrict__ xs, const unsigned short* __restrict__ xts,
    const unsigned short* __restrict__ wcat, const float* __restrict__ bcat,
    unsigned short* __restrict__ Q, unsigned short* __restrict__ K,
    unsigned short* __restrict__ Vt) {
  __shared__ unsigned short lA[128 * 32];
  __shared__ unsigned short lB[128 * 32];
  const int t = threadIdx.x;
  const int m0 = blockIdx.y * 128, n0 = blockIdx.x * 128, b = blockIdx.z;
  const int seg = n0 >> 9;
  const unsigned short* A = ((seg == 0) ? xs : xts) + (size_t)b * 2304 * 768 + (size_t)m0 * 768;
  const unsigned short* Bt = wcat + (size_t)n0 * 768;
  const int lane = t & 63, wid = t >> 6;
  const int wm = (wid & 1) * 64, wn = (wid >> 1) * 64;
  const int fr = lane & 15, fq = lane >> 4;
  f32x4 acc[4][4] = {};

  for (int k0 = 0; k0 < 768; k0 += 32) {
#pragma unroll
    for (int it = 0; it < 2; ++it) {
      const int c = it * 256 + t;
      const int row = c >> 2, k8 = (c & 3) << 3;
      __builtin_amdgcn_global_load_lds(
          (const __attribute__((address_space(1))) void*)(A + (size_t)row * 768 + k0 + k8),
          (__attribute__((address_space(3))) void*)(&lA[c * 8]), 16, 0, 0);
      __builtin_amdgcn_global_load_lds(
          (const __attribute__((address_space(1))) void*)(Bt + (size_t)row * 768 + k0 + k8),
          (__attribute__((address_space(3))) void*)(&lB[c * 8]), 16, 0, 0);
    }
    __syncthreads();
    bf16x8 af[4], bfr[4];
#pragma unroll
    for (int i = 0; i < 4; ++i)
      af[i] = *reinterpret_cast<const bf16x8*>(&lA[(wm + i * 16 + fr) * 32 + fq * 8]);
#pragma unroll
    for (int j = 0; j < 4; ++j)
      bfr[j] = *reinterpret_cast<const bf16x8*>(&lB[(wn + j * 16 + fr) * 32 + fq * 8]);
#pragma unroll
    for (int i = 0; i < 4; ++i)
#pragma unroll
      for (int j = 0; j < 4; ++j)
        acc[i][j] = __builtin_amdgcn_mfma_f32_16x16x32_bf16(af[i], bfr[j], acc[i][j], 0, 0, 0);
    __syncthreads();
  }

  if (seg < 2) {
    unsigned short* Cp = ((seg == 0) ? Q : K) + (size_t)b * 2304 * 512;
#pragma unroll
    for (int j = 0; j < 4; ++j) {
      const int ng = n0 + wn + j * 16 + fr;
      const float bj = bcat[ng];
      const int col = ng - seg * 512;
#pragma unroll
      for (int i = 0; i < 4; ++i) {
        const int rbase = m0 + wm + i * 16 + fq * 4;
#pragma unroll
        for (int r = 0; r < 4; ++r)
          Cp[(size_t)(rbase + r) * 512 + col] = f2bf(acc[i][j][r] + bj);
      }
    }
  } else {
    unsigned short* Cp = Vt + (size_t)b * 512 * 2304;
#pragma unroll
    for (int j = 0; j < 4; ++j) {
      const int ng = n0 + wn + j * 16 + fr;
      const float bj = bcat[ng];
      const int d = ng - 1024;
#pragma unroll
      for (int i = 0; i < 4; ++i) {
        const int tb = m0 + wm + i * 16 + fq * 4;
        ushort4 pk;
        pk.x = f2bf(acc[i][j][0] + bj);
        pk.y = f2bf(acc[i][j][1] + bj);
        pk.z = f2bf(acc[i][j][2] + bj);
        pk.w = f2bf(acc[i][j][3] + bj);
        *reinterpret_cast<ushort4*>(&Cp[(size_t)d * 2304 + tb]) = pk;
      }
    }
  }
}

// ---- scores: 256x256 tile, 8 waves (2m x 4n), BK=32, dbuf ----
// T3-minimum schedule: STAGE(next tile) issued BEFORE ds_read+MFMA(current),
// one __syncthreads() (vmcnt+lgkm drain) per K-tile.
// P = exp(Q K^T * scale - 4) bf16; denom[row] += rowsum (atomic)
__global__ __launch_bounds__(512, 2) void scores256_kernel(
    const unsigned short* __restrict__ Qm, const unsigned short* __restrict__ Km,
    float* __restrict__ denom, unsigned short* __restrict__ P) {
  __shared__ unsigned short lA[2][8192];
  __shared__ unsigned short lB[2][8192];
  const int t = threadIdx.x;
  const int m0 = blockIdx.y * 256, n0 = blockIdx.x * 256, b = blockIdx.z;
  const unsigned short* Ag = Qm + (size_t)b * 2304 * 512 + (size_t)m0 * 512;
  const unsigned short* Bg = Km + (size_t)b * 2304 * 512 + (size_t)n0 * 512;
  const int lane = t & 63, wid = t >> 6;
  const int wr = wid >> 2, wc = wid & 3;
  const int fr = lane & 15, fq = lane >> 4;
  // staging: 16B chunk L = {t, 512+t}; row = L>>2, k8 = (L&3)*8 (BK=32)
  const size_t a0 = (size_t)(t >> 2) * 512 + (size_t)(t & 3) * 8;
  const size_t a1 = (size_t)(128 + (t >> 2)) * 512 + (size_t)(t & 3) * 8;
  f32x4 acc[8][4] = {};

#define STAGE(buf, k0)                                                                         \
  {                                                                                            \
    __builtin_amdgcn_global_load_lds(                                                          \
        (const __attribute__((address_space(1))) void*)(Ag + a0 + (k0)),                       \
        (__attribute__((address_space(3))) void*)(&lA[buf][(size_t)t * 8]), 16, 0, 0);         \
    __builtin_amdgcn_global_load_lds(                                                          \
        (const __attribute__((address_space(1))) void*)(Ag + a1 + (k0)),                       \
        (__attribute__((address_space(3))) void*)(&lA[buf][(size_t)(512 + t) * 8]), 16, 0, 0); \
    __builtin_amdgcn_global_load_lds(                                                          \
        (const __attribute__((address_space(1))) void*)(Bg + a0 + (k0)),                       \
        (__attribute__((address_space(3))) void*)(&lB[buf][(size_t)t * 8]), 16, 0, 0);         \
    __builtin_amdgcn_global_load_lds(                                                          \
        (const __attribute__((address_space(1))) void*)(Bg + a1 + (k0)),                       \
        (__attribute__((address_space(3))) void*)(&lB[buf][(size_t)(512 + t) * 8]), 16, 0, 0); \
  }

  STAGE(0, 0);
  __syncthreads();  // drains vmcnt: buf0 ready

  for (int kt = 0; kt < 16; ++kt) {
    const int cur = kt & 1;
    // issue next tile's 4 loads FIRST (land in buf^1, gated by end-of-iter barrier)
    if (kt < 15) STAGE(cur ^ 1, (kt + 1) * 32);
    bf16x8 af[8], bfr[4];
#pragma unroll
    for (int j = 0; j < 4; ++j)
      bfr[j] = *reinterpret_cast<const bf16x8*>(&lB[cur][(wc * 64 + j * 16 + fr) * 32 + fq * 8]);
#pragma unroll
    for (int i = 0; i < 8; ++i)
      af[i] = *reinterpret_cast<const bf16x8*>(&lA[cur][(wr * 128 + i * 16 + fr) * 32 + fq * 8]);
#pragma unroll
    for (int i = 0; i < 8; ++i)
#pragma unroll
      for (int j = 0; j < 4; ++j)
        acc[i][j] = __builtin_amdgcn_mfma_f32_16x16x32_bf16(af[i], bfr[j], acc[i][j], 0, 0, 0);
    __syncthreads();  // one drain+barrier per K-tile: buf^1 ready, buf reusable
  }
#undef STAGE

  // epilogue: exp + bf16 store + atomic row denominators
  unsigned short* Pp = P + (size_t)b * 2304 * 2304;
  const float SC = 0.044194173824159216f;
#pragma unroll
  for (int i = 0; i < 8; ++i) {
    float rs[4] = {0.f, 0.f, 0.f, 0.f};
    const int rbase = m0 + wr * 128 + i * 16 + fq * 4;
#pragma unroll
    for (int j = 0; j < 4; ++j) {
      const int col = n0 + wc * 64 + j * 16 + fr;
#pragma unroll
      for (int r = 0; r < 4; ++r) {
        const float e = __expf(acc[i][j][r] * SC - 4.0f);
        rs[r] += e;
        Pp[(size_t)(rbase + r) * 2304 + col] = f2bf(e);
      }
    }
#pragma unroll
    for (int r = 0; r < 4; ++r) {
      float s = rs[r];
#pragma unroll
      for (int o = 8; o >= 1; o >>= 1) s += __shfl_xor(s, o, 16);
      if (fr == 0) atomicAdd(&denom[(size_t)b * 2304 + rbase + r], s);
    }
  }
}

// ---- PV: m97 128^2, out = (P @ Vt^T) / denom[row], fp32 ----
__global__ __launch_bounds__(256) void pv_kernel(
    const unsigned short* __restrict__ P, const unsigned short* __restrict__ Vt,
    const float* __restrict__ denom, float* __restrict__ Out) {
  __shared__ unsigned short lA[128 * 32];
  __shared__ unsigned short lB[128 * 32];
  const int t = threadIdx.x;
  const int m0 = blockIdx.y * 128, n0 = blockIdx.x * 128, b = blockIdx.z;
  const unsigned short* A = P + (size_t)b * 2304 * 2304 + (size_t)m0 * 2304;
  const unsigned short* Bt = Vt + (size_t)b * 512 * 2304 + (size_t)n0 * 2304;
  const int lane = t & 63, wid = t >> 6;
  const int wm = (wid & 1) * 64, wn = (wid >> 1) * 64;
  const int fr = lane & 15, fq = lane >> 4;
  f32x4 acc[4][4] = {};

  for (int k0 = 0; k0 < 2304; k0 += 32) {
#pragma unroll
    for (int it = 0; it < 2; ++it) {
      const int c = it * 256 + t;
      const int row = c >> 2, k8 = (c & 3) << 3;
      __builtin_amdgcn_global_load_lds(
          (const __attribute__((address_space(1))) void*)(A + (size_t)row * 2304 + k0 + k8),
          (__attribute__((address_space(3))) void*)(&lA[c * 8]), 16, 0, 0);
      __builtin_amdgcn_global_load_lds(
          (const __attribute__((address_space(1))) void*)(Bt + (size_t)row * 2304 + k0 + k8),
          (__attribute__((address_space(3))) void*)(&lB[c * 8]), 16, 0, 0);
    }
    __syncthreads();
    bf16x8 af[4], bfr[4];
#pragma unroll
    for (int i = 0; i < 4; ++i)
      af[i] = *reinterpret_cast<const bf16x8*>(&lA[(wm + i * 16 + fr) * 32 + fq * 8]);
#pragma unroll
    for (int j = 0; j < 4; ++j)
      bfr[j] = *reinterpret_cast<const bf16x8*>(&lB[(wn + j * 16 + fr) * 32 + fq * 8]);
#pragma unroll
    for (int i = 0; i < 4; ++i)
#pragma unroll
      for (int j = 0; j < 4; ++j)
        acc[i][j] = __builtin_amdgcn_mfma_f32_16x16x32_bf16(af[i], bfr[j], acc[i][j], 0, 0, 0);
    __syncthreads();
  }

  float* Cp = Out + (size_t)b * 2304 * 512;
  float invd[4][4];
#pragma unroll
  for (int i = 0; i < 4; ++i)
#pragma unroll
    for (int r = 0; r < 4; ++r)
      invd[i][r] = 1.0f / denom[(size_t)b * 2304 + m0 + wm + i * 16 + fq * 4 + r];
#pragma unroll
  for (int j = 0; j < 4; ++j) {
    const int col = n0 + wn + j * 16 + fr;
#pragma unroll
    for (int i = 0; i < 4; ++i) {
      const int rbase = m0 + wm + i * 16 + fq * 4;
#pragma unroll
      for (int r = 0; r < 4; ++r)
        Cp[(size_t)(rbase + r) * 512 + col] = acc[i][j][r] * invd[i][r];
    }
  }
}

extern "C" void kernel_launch(void* const* d_in, const int* in_sizes, int n_in,
                              void* d_out, int out_size, void* d_ws, size_t ws_size,
                              hipStream_t stream) {
  const float* x  = (const float*)d_in[0];
  const float* xt = (const float*)d_in[1];
  const float* wq = (const float*)d_in[2];
  const float* bq = (const float*)d_in[3];
  const float* wk = (const float*)d_in[4];
  const float* bk = (const float*)d_in[5];
  const float* wv = (const float*)d_in[6];
  const float* bv = (const float*)d_in[7];
  float* out = (float*)d_out;
  unsigned short* ws = (unsigned short*)d_ws;

  unsigned short* Q    = ws;
  unsigned short* Kb   = ws + 9437184;
  unsigned short* Vt   = ws + 18874368;
  unsigned short* P    = ws + 28311552;   // 85MB region
  unsigned short* xs   = ws + 28311552;   // aliases P (dead before P written)
  unsigned short* xts  = ws + 42467328;
  unsigned short* wcat = ws + 56623104;   // wq|wk|wv contiguous (1536x768)
  float* bcat  = (float*)(ws + 57802752); // 1536 f32 (inside P region, dead early)
  float* denom = (float*)(ws + 70778880); // 18432 f32, after P

  convw_kernel<<<384, 256, 0, stream>>>(wq, wcat, 393216);
  convw_kernel<<<384, 256, 0, stream>>>(wk, wcat + 393216, 393216);
  convw_kernel<<<384, 256, 0, stream>>>(wv, wcat + 786432, 393216);
  init_kernel<<<78, 256, 0, stream>>>(bq, bk, bv, denom, bcat);
  transpose_bf16_kernel<<<dim3(36, 12, 16), 256, 0, stream>>>(x, xt, xs, xts);

  // fused Q|K|V projection
  qkv_kernel<<<dim3(12, 18, 8), 256, 0, stream>>>(xs, xts, wcat, bcat, Q, Kb, Vt);

  // P = exp(Q K^T / sqrt(D) - 4), denom[row] = sum_t P
  scores256_kernel<<<dim3(9, 9, 8), 512, 0, stream>>>(Q, Kb, denom, P);

  // out = (P @ V) / denom[row]
  pv_kernel<<<dim3(4, 18, 8), 256, 0, stream>>>(P, Vt, denom, out);
}

// Round 5
// 293.956 us; speedup vs baseline: 1.0740x; 1.0740x over previous
//
#include <hip/hip_runtime.h>
#include <stdint.h>

// CrossAttentionHead: B=8, C=768, S=T=2304, D=512.
// transpose/cvt -> fused QKV GEMM (N=1536 concat) -> scores128 (m97 128^2,
// grid 2592 = 10 blocks/CU, exp epilogue + atomic row denom) -> PV GEMM
// (m97 128^2, 1/denom epilogue).
//
// Round-5 note: 256^2 scores tile reverted (2 blocks/CU -> latency-bound,
// 120us vs 98-100us at 128^2/2592 blocks; two different 2ph schedules
// measured identical => TLP, not scheduling, is the lever at these shapes).
//
// Workspace (ushort elems):
//   Q[0,..) K[9437184,..) Vt[18874368,..)  (each 9,437,184)
//   P@28311552 (42,467,328 elems, 85MB); aliased inside P (dead before P):
//   xs@28311552, xts@42467328, wcat@56623104 (wq|wk|wv, 1536x768),
//   bcat(f32)@ushort 57802752; denom(f32,18432)@ushort 70778880.

typedef __bf16 bf16x8 __attribute__((ext_vector_type(8)));
typedef float f32x4 __attribute__((ext_vector_type(4)));

__device__ __forceinline__ unsigned short f2bf(float f) {
  union { float f; unsigned int u; } c; c.f = f;
  return (unsigned short)((c.u + 0x7fffu + ((c.u >> 16) & 1u)) >> 16); // RNE
}

// ---- all three weights fp32 -> bf16 into contiguous wcat ----
__global__ __launch_bounds__(256) void convw3_kernel(const float* __restrict__ wq,
                                                     const float* __restrict__ wk,
                                                     const float* __restrict__ wv,
                                                     unsigned short* __restrict__ wcat) {
  int i = (blockIdx.x * 256 + threadIdx.x) * 4;  // 0 .. 1179644
  const float* src = (i < 393216) ? wq : (i < 786432) ? wk : wv;
  const int off = (i < 393216) ? 0 : (i < 786432) ? 393216 : 786432;
  const float4 v = *reinterpret_cast<const float4*>(src + (i - off));
  wcat[i + 0] = f2bf(v.x); wcat[i + 1] = f2bf(v.y);
  wcat[i + 2] = f2bf(v.z); wcat[i + 3] = f2bf(v.w);
}

// ---- zero denom + concat bias ----
__global__ __launch_bounds__(256) void init_kernel(const float* __restrict__ bq,
                                                   const float* __restrict__ bk,
                                                   const float* __restrict__ bv,
                                                   float* __restrict__ denom,
                                                   float* __restrict__ bcat) {
  int i = blockIdx.x * 256 + threadIdx.x;
  if (i < 18432) denom[i] = 0.0f;
  else if (i < 19968) {
    int k = i - 18432;
    bcat[k] = (k < 512) ? bq[k] : (k < 1024) ? bk[k - 512] : bv[k - 1024];
  }
}

// ---- x[b][c][s] fp32 -> xs[b][s][c] bf16 (64x64 LDS tiles) ----
__global__ __launch_bounds__(256) void transpose_bf16_kernel(
    const float* __restrict__ x, const float* __restrict__ xt,
    unsigned short* __restrict__ xs, unsigned short* __restrict__ xts) {
  const int S = 2304, C = 768;
  const int z = blockIdx.z;
  const float* src = (z < 8) ? x : xt;
  unsigned short* dst = (z < 8) ? xs : xts;
  const int b = z & 7;
  src += (size_t)b * C * S;
  dst += (size_t)b * S * C;
  __shared__ float tile[64][65];
  const int s0 = blockIdx.x * 64, c0 = blockIdx.y * 64;
  const int ls = threadIdx.x & 63, lr = threadIdx.x >> 6;
#pragma unroll
  for (int i = 0; i < 16; ++i) {
    const int c = lr + i * 4;
    tile[c][ls] = src[(size_t)(c0 + c) * S + s0 + ls];
  }
  __syncthreads();
#pragma unroll
  for (int i = 0; i < 16; ++i) {
    const int s = lr + i * 4;
    dst[(size_t)(s0 + s) * C + c0 + ls] = f2bf(tile[ls][s]);
  }
}

// ---- fused QKV projection: C[m][0..1536) = A @ wcat^T + bcat (m97 128^2) ----
// seg 0 -> Q[m][n], seg 1 -> K[m][n-512], seg 2 -> Vt[n-1024][m]
__global__ __launch_bounds__(256) void qkv_kernel(
    const unsigned short* __restrict__ xs, const unsigned short* __restrict__ xts,
    const unsigned short* __restrict__ wcat, const float* __restrict__ bcat,
    unsigned short* __restrict__ Q, unsigned short* __restrict__ K,
    unsigned short* __restrict__ Vt) {
  __shared__ unsigned short lA[128 * 32];
  __shared__ unsigned short lB[128 * 32];
  const int t = threadIdx.x;
  const int m0 = blockIdx.y * 128, n0 = blockIdx.x * 128, b = blockIdx.z;
  const int seg = n0 >> 9;
  const unsigned short* A = ((seg == 0) ? xs : xts) + (size_t)b * 2304 * 768 + (size_t)m0 * 768;
  const unsigned short* Bt = wcat + (size_t)n0 * 768;
  const int lane = t & 63, wid = t >> 6;
  const int wm = (wid & 1) * 64, wn = (wid >> 1) * 64;
  const int fr = lane & 15, fq = lane >> 4;
  f32x4 acc[4][4] = {};

  for (int k0 = 0; k0 < 768; k0 += 32) {
#pragma unroll
    for (int it = 0; it < 2; ++it) {
      const int c = it * 256 + t;
      const int row = c >> 2, k8 = (c & 3) << 3;
      __builtin_amdgcn_global_load_lds(
          (const __attribute__((address_space(1))) void*)(A + (size_t)row * 768 + k0 + k8),
          (__attribute__((address_space(3))) void*)(&lA[c * 8]), 16, 0, 0);
      __builtin_amdgcn_global_load_lds(
          (const __attribute__((address_space(1))) void*)(Bt + (size_t)row * 768 + k0 + k8),
          (__attribute__((address_space(3))) void*)(&lB[c * 8]), 16, 0, 0);
    }
    __syncthreads();
    bf16x8 af[4], bfr[4];
#pragma unroll
    for (int i = 0; i < 4; ++i)
      af[i] = *reinterpret_cast<const bf16x8*>(&lA[(wm + i * 16 + fr) * 32 + fq * 8]);
#pragma unroll
    for (int j = 0; j < 4; ++j)
      bfr[j] = *reinterpret_cast<const bf16x8*>(&lB[(wn + j * 16 + fr) * 32 + fq * 8]);
#pragma unroll
    for (int i = 0; i < 4; ++i)
#pragma unroll
      for (int j = 0; j < 4; ++j)
        acc[i][j] = __builtin_amdgcn_mfma_f32_16x16x32_bf16(af[i], bfr[j], acc[i][j], 0, 0, 0);
    __syncthreads();
  }

  if (seg < 2) {
    unsigned short* Cp = ((seg == 0) ? Q : K) + (size_t)b * 2304 * 512;
#pragma unroll
    for (int j = 0; j < 4; ++j) {
      const int ng = n0 + wn + j * 16 + fr;
      const float bj = bcat[ng];
      const int col = ng - seg * 512;
#pragma unroll
      for (int i = 0; i < 4; ++i) {
        const int rbase = m0 + wm + i * 16 + fq * 4;
#pragma unroll
        for (int r = 0; r < 4; ++r)
          Cp[(size_t)(rbase + r) * 512 + col] = f2bf(acc[i][j][r] + bj);
      }
    }
  } else {
    unsigned short* Cp = Vt + (size_t)b * 512 * 2304;
#pragma unroll
    for (int j = 0; j < 4; ++j) {
      const int ng = n0 + wn + j * 16 + fr;
      const float bj = bcat[ng];
      const int d = ng - 1024;
#pragma unroll
      for (int i = 0; i < 4; ++i) {
        const int tb = m0 + wm + i * 16 + fq * 4;
        ushort4 pk;
        pk.x = f2bf(acc[i][j][0] + bj);
        pk.y = f2bf(acc[i][j][1] + bj);
        pk.z = f2bf(acc[i][j][2] + bj);
        pk.w = f2bf(acc[i][j][3] + bj);
        *reinterpret_cast<ushort4*>(&Cp[(size_t)d * 2304 + tb]) = pk;
      }
    }
  }
}

// ---- scores: m97 128^2, grid (18,18,8)=2592 blocks (10/CU) ----
// P = exp(Q K^T * scale - 4) bf16; denom[row] += rowsum (atomic)
__global__ __launch_bounds__(256) void scores128_kernel(
    const unsigned short* __restrict__ Qm, const unsigned short* __restrict__ Km,
    float* __restrict__ denom, unsigned short* __restrict__ P) {
  __shared__ unsigned short lA[128 * 32];
  __shared__ unsigned short lB[128 * 32];
  const int t = threadIdx.x;
  const int m0 = blockIdx.y * 128, n0 = blockIdx.x * 128, b = blockIdx.z;
  const unsigned short* A = Qm + (size_t)b * 2304 * 512 + (size_t)m0 * 512;
  const unsigned short* Bt = Km + (size_t)b * 2304 * 512 + (size_t)n0 * 512;
  const int lane = t & 63, wid = t >> 6;
  const int wm = (wid & 1) * 64, wn = (wid >> 1) * 64;
  const int fr = lane & 15, fq = lane >> 4;
  f32x4 acc[4][4] = {};

  for (int k0 = 0; k0 < 512; k0 += 32) {
#pragma unroll
    for (int it = 0; it < 2; ++it) {
      const int c = it * 256 + t;
      const int row = c >> 2, k8 = (c & 3) << 3;
      __builtin_amdgcn_global_load_lds(
          (const __attribute__((address_space(1))) void*)(A + (size_t)row * 512 + k0 + k8),
          (__attribute__((address_space(3))) void*)(&lA[c * 8]), 16, 0, 0);
      __builtin_amdgcn_global_load_lds(
          (const __attribute__((address_space(1))) void*)(Bt + (size_t)row * 512 + k0 + k8),
          (__attribute__((address_space(3))) void*)(&lB[c * 8]), 16, 0, 0);
    }
    __syncthreads();
    bf16x8 af[4], bfr[4];
#pragma unroll
    for (int i = 0; i < 4; ++i)
      af[i] = *reinterpret_cast<const bf16x8*>(&lA[(wm + i * 16 + fr) * 32 + fq * 8]);
#pragma unroll
    for (int j = 0; j < 4; ++j)
      bfr[j] = *reinterpret_cast<const bf16x8*>(&lB[(wn + j * 16 + fr) * 32 + fq * 8]);
#pragma unroll
    for (int i = 0; i < 4; ++i)
#pragma unroll
      for (int j = 0; j < 4; ++j)
        acc[i][j] = __builtin_amdgcn_mfma_f32_16x16x32_bf16(af[i], bfr[j], acc[i][j], 0, 0, 0);
    __syncthreads();
  }

  // epilogue: exp + bf16 store + atomic row denominators (validated round 2)
  unsigned short* Pp = P + (size_t)b * 2304 * 2304;
  const float SC = 0.044194173824159216f;
  float rowsum[4][4];
#pragma unroll
  for (int i = 0; i < 4; ++i)
#pragma unroll
    for (int r = 0; r < 4; ++r) rowsum[i][r] = 0.0f;
#pragma unroll
  for (int j = 0; j < 4; ++j) {
    const int col = n0 + wn + j * 16 + fr;
#pragma unroll
    for (int i = 0; i < 4; ++i) {
      const int rbase = m0 + wm + i * 16 + fq * 4;
#pragma unroll
      for (int r = 0; r < 4; ++r) {
        const float e = __expf(acc[i][j][r] * SC - 4.0f);
        rowsum[i][r] += e;
        Pp[(size_t)(rbase + r) * 2304 + col] = f2bf(e);
      }
    }
  }
#pragma unroll
  for (int i = 0; i < 4; ++i)
#pragma unroll
    for (int r = 0; r < 4; ++r) {
      float s = rowsum[i][r];
#pragma unroll
      for (int o = 8; o >= 1; o >>= 1) s += __shfl_xor(s, o, 16);
      if (fr == 0)
        atomicAdd(&denom[(size_t)b * 2304 + m0 + wm + i * 16 + fq * 4 + r], s);
    }
}

// ---- PV: m97 128^2, out = (P @ Vt^T) / denom[row], fp32 ----
__global__ __launch_bounds__(256) void pv_kernel(
    const unsigned short* __restrict__ P, const unsigned short* __restrict__ Vt,
    const float* __restrict__ denom, float* __restrict__ Out) {
  __shared__ unsigned short lA[128 * 32];
  __shared__ unsigned short lB[128 * 32];
  const int t = threadIdx.x;
  const int m0 = blockIdx.y * 128, n0 = blockIdx.x * 128, b = blockIdx.z;
  const unsigned short* A = P + (size_t)b * 2304 * 2304 + (size_t)m0 * 2304;
  const unsigned short* Bt = Vt + (size_t)b * 512 * 2304 + (size_t)n0 * 2304;
  const int lane = t & 63, wid = t >> 6;
  const int wm = (wid & 1) * 64, wn = (wid >> 1) * 64;
  const int fr = lane & 15, fq = lane >> 4;
  f32x4 acc[4][4] = {};

  for (int k0 = 0; k0 < 2304; k0 += 32) {
#pragma unroll
    for (int it = 0; it < 2; ++it) {
      const int c = it * 256 + t;
      const int row = c >> 2, k8 = (c & 3) << 3;
      __builtin_amdgcn_global_load_lds(
          (const __attribute__((address_space(1))) void*)(A + (size_t)row * 2304 + k0 + k8),
          (__attribute__((address_space(3))) void*)(&lA[c * 8]), 16, 0, 0);
      __builtin_amdgcn_global_load_lds(
          (const __attribute__((address_space(1))) void*)(Bt + (size_t)row * 2304 + k0 + k8),
          (__attribute__((address_space(3))) void*)(&lB[c * 8]), 16, 0, 0);
    }
    __syncthreads();
    bf16x8 af[4], bfr[4];
#pragma unroll
    for (int i = 0; i < 4; ++i)
      af[i] = *reinterpret_cast<const bf16x8*>(&lA[(wm + i * 16 + fr) * 32 + fq * 8]);
#pragma unroll
    for (int j = 0; j < 4; ++j)
      bfr[j] = *reinterpret_cast<const bf16x8*>(&lB[(wn + j * 16 + fr) * 32 + fq * 8]);
#pragma unroll
    for (int i = 0; i < 4; ++i)
#pragma unroll
      for (int j = 0; j < 4; ++j)
        acc[i][j] = __builtin_amdgcn_mfma_f32_16x16x32_bf16(af[i], bfr[j], acc[i][j], 0, 0, 0);
    __syncthreads();
  }

  float* Cp = Out + (size_t)b * 2304 * 512;
  float invd[4][4];
#pragma unroll
  for (int i = 0; i < 4; ++i)
#pragma unroll
    for (int r = 0; r < 4; ++r)
      invd[i][r] = 1.0f / denom[(size_t)b * 2304 + m0 + wm + i * 16 + fq * 4 + r];
#pragma unroll
  for (int j = 0; j < 4; ++j) {
    const int col = n0 + wn + j * 16 + fr;
#pragma unroll
    for (int i = 0; i < 4; ++i) {
      const int rbase = m0 + wm + i * 16 + fq * 4;
#pragma unroll
      for (int r = 0; r < 4; ++r)
        Cp[(size_t)(rbase + r) * 512 + col] = acc[i][j][r] * invd[i][r];
    }
  }
}

extern "C" void kernel_launch(void* const* d_in, const int* in_sizes, int n_in,
                              void* d_out, int out_size, void* d_ws, size_t ws_size,
                              hipStream_t stream) {
  const float* x  = (const float*)d_in[0];
  const float* xt = (const float*)d_in[1];
  const float* wq = (const float*)d_in[2];
  const float* bq = (const float*)d_in[3];
  const float* wk = (const float*)d_in[4];
  const float* bk = (const float*)d_in[5];
  const float* wv = (const float*)d_in[6];
  const float* bv = (const float*)d_in[7];
  float* out = (float*)d_out;
  unsigned short* ws = (unsigned short*)d_ws;

  unsigned short* Q    = ws;
  unsigned short* Kb   = ws + 9437184;
  unsigned short* Vt   = ws + 18874368;
  unsigned short* P    = ws + 28311552;   // 85MB region
  unsigned short* xs   = ws + 28311552;   // aliases P (dead before P written)
  unsigned short* xts  = ws + 42467328;
  unsigned short* wcat = ws + 56623104;   // wq|wk|wv contiguous (1536x768)
  float* bcat  = (float*)(ws + 57802752); // 1536 f32 (inside P region, dead early)
  float* denom = (float*)(ws + 70778880); // 18432 f32, after P

  convw3_kernel<<<1152, 256, 0, stream>>>(wq, wk, wv, wcat);
  init_kernel<<<78, 256, 0, stream>>>(bq, bk, bv, denom, bcat);
  transpose_bf16_kernel<<<dim3(36, 12, 16), 256, 0, stream>>>(x, xt, xs, xts);

  // fused Q|K|V projection
  qkv_kernel<<<dim3(12, 18, 8), 256, 0, stream>>>(xs, xts, wcat, bcat, Q, Kb, Vt);

  // P = exp(Q K^T / sqrt(D) - 4), denom[row] = sum_t P
  scores128_kernel<<<dim3(18, 18, 8), 256, 0, stream>>>(Q, Kb, denom, P);

  // out = (P @ V) / denom[row]
  pv_kernel<<<dim3(4, 18, 8), 256, 0, stream>>>(P, Vt, denom, out);
}